// Round 8
// baseline (57.321 us; speedup 1.0000x reference)
//
#include <hip/hip_runtime.h>

#define NS 8192
#define MS 2048
#define DD 32
#define MSPLIT 32
#define REPEAT 4   // DIAGNOSTIC: multiply main-kernel work so it exceeds the
                   // ~39us harness fill kernels and becomes visible in top-5
                   // rocprof slots. Output scaled by 1/REPEAT (exactness: adds
                   // ~1e-13 fp32 noise vs 4.5e-8 threshold). Remove next round.

typedef __attribute__((ext_vector_type(8))) short bf16x8;
typedef __attribute__((ext_vector_type(4))) float f32x4;
typedef unsigned short u16;

// ---- ws byte offsets ----
#define WH_OFF   (0)                        // [M][64] bf16 hi
#define WL_OFF   (256*1024)                 // [M][64] bf16 lo
#define XH_OFF   (512*1024)                 // [N][32] s  hi
#define XL_OFF   (1024*1024)                // [N][32] s  lo
#define QH_OFF   (1536*1024)                // [N][32] s^2 hi
#define QL_OFF   (2048*1024)                // [N][32] s^2 lo
#define A2_OFF   (2560*1024)                // [M] f32
#define PART_OFF (A2_OFF + 8*1024)          // [MSPLIT][N] f32
#define DIST_OFF (PART_OFF + MSPLIT*NS*4)
#define MM_OFF   (DIST_OFF + NS*4)          // 2 u32 (min,max bits)
#define CNT_OFF  (MM_OFF + 8)               // 1 u32

__device__ inline float fast_exp2(float x) {
#if __has_builtin(__builtin_amdgcn_exp2f)
    return __builtin_amdgcn_exp2f(x);
#else
    return exp2f(x);
#endif
}
__device__ inline u16 f2bf(float x) {  // round-to-nearest-even bf16
    unsigned u = __float_as_uint(x);
    return (u16)((u + 0x7fffu + ((u >> 16) & 1u)) >> 16);
}
__device__ inline float bf2f(u16 h) { return __uint_as_float(((unsigned)h) << 16); }

// prep (round-5, proven): balanced W path (64 blocks) + X path (256 blocks).
__global__ __launch_bounds__(256) void prep_kernel(const float* __restrict__ samples,
                                                   const float* __restrict__ means,
                                                   const float* __restrict__ stds,
                                                   unsigned char* __restrict__ ws) {
    const int tid = threadIdx.x, bid = blockIdx.x;
    if (bid == 0 && tid == 0) {
        unsigned* mm = (unsigned*)(ws + MM_OFF);
        mm[0] = 0x7f7fffffu;  // FLT_MAX bits
        mm[1] = 0u;
        *(unsigned*)(ws + CNT_OFF) = 0u;
    }
    if (bid < 64) {
        const int p = bid * 256 + tid;        // < 16384
        const int m = p >> 3;
        const int c = p & 7;                  // c<4 -> B rows, c>=4 -> C rows
        const int d0 = (c & 3) * 8;
        const bool isB = (c < 4);

        const float4* mrow = (const float4*)(means + (size_t)m * DD + d0);
        const float4* srow = (const float4*)(stds  + (size_t)m * DD + d0);
        float4 mu4a = mrow[0], mu4b = mrow[1];
        float4 sd4a = srow[0], sd4b = srow[1];
        float mu[8] = {mu4a.x, mu4a.y, mu4a.z, mu4a.w, mu4b.x, mu4b.y, mu4b.z, mu4b.w};
        float sd[8] = {sd4a.x, sd4a.y, sd4a.z, sd4a.w, sd4b.x, sd4b.y, sd4b.z, sd4b.w};

        const float L2E = 1.4426950408889634f;
        float a = 0.f;
        ushort4 h0, h1, l0, l1;
        u16* ph = (u16*)&h0; u16* ph1 = (u16*)&h1;
        u16* pl = (u16*)&l0; u16* pl1 = (u16*)&l1;
#pragma unroll
        for (int e = 0; e < 8; ++e) {
            float inv = 1.0f / sd[e];
            float val = isB ? (L2E * mu[e] * inv) : (-0.5f * L2E * inv);
            if (isB) a += mu[e] * mu[e] * inv;
            u16 h = f2bf(val);
            u16 l = f2bf(val - bf2f(h));
            if (e < 4) { ph[e] = h; pl[e] = l; }
            else       { ph1[e - 4] = h; pl1[e - 4] = l; }
        }
        a += __shfl_xor(a, 1);
        a += __shfl_xor(a, 2);
        a += __shfl_xor(a, 4);
        if (c == 0) ((float*)(ws + A2_OFF))[m] = -0.5f * L2E * a - 11.0f;

        u16* WH = (u16*)(ws + WH_OFF) + (size_t)m * 64 + c * 8;
        u16* WL = (u16*)(ws + WL_OFF) + (size_t)m * 64 + c * 8;
        *(ushort4*)(WH)     = h0;
        *(ushort4*)(WH + 4) = h1;
        *(ushort4*)(WL)     = l0;
        *(ushort4*)(WL + 4) = l1;
    } else {
        const int idx = (bid - 64) * 256 + tid;  // < NS*DD/4
        float4 v = ((const float4*)samples)[idx];
        float xs[4] = {v.x, v.y, v.z, v.w};
        ushort4 hx, lx, hq, lq;
        u16* ph = (u16*)&hx; u16* pl = (u16*)&lx;
        u16* qh = (u16*)&hq; u16* ql = (u16*)&lq;
#pragma unroll
        for (int j = 0; j < 4; ++j) {
            float x = xs[j];
            u16 h = f2bf(x);
            ph[j] = h;
            pl[j] = f2bf(x - bf2f(h));
            float q = x * x;
            u16 hh = f2bf(q);
            qh[j] = hh;
            ql[j] = f2bf(q - bf2f(hh));
        }
        *(ushort4*)((u16*)(ws + XH_OFF) + idx * 4) = hx;
        *(ushort4*)((u16*)(ws + XL_OFF) + idx * 4) = lx;
        *(ushort4*)((u16*)(ws + QH_OFF) + idx * 4) = hq;
        *(ushort4*)((u16*)(ws + QL_OFF) + idx * 4) = lq;
    }
}

// R5's main kernel, UNCHANGED except the diagnostic REPEAT loop.
__global__ __launch_bounds__(256, 3) void kde_mfma(const unsigned char* __restrict__ ws,
                                                   float* __restrict__ partial) {
    const u16* XH = (const u16*)(ws + XH_OFF);
    const u16* XL = (const u16*)(ws + XL_OFF);
    const u16* QH = (const u16*)(ws + QH_OFF);
    const u16* QL = (const u16*)(ws + QL_OFF);
    const u16* WH = (const u16*)(ws + WH_OFF);
    const u16* WL = (const u16*)(ws + WL_OFF);
    const float* A2 = (const float*)(ws + A2_OFF);

    const int lane = threadIdx.x & 63, wid = threadIdx.x >> 6;
    const int r15 = lane & 15, g = lane >> 4;
    const int n_base = (blockIdx.x * 4 + wid) * 64;

    bf16x8 xh[4], xl[4], qh[4], ql[4];
#pragma unroll
    for (int nt = 0; nt < 4; ++nt) {
        const size_t off = (size_t)(n_base + nt * 16 + r15) * DD + g * 8;
        xh[nt] = *(const bf16x8*)(XH + off);
        xl[nt] = *(const bf16x8*)(XL + off);
        qh[nt] = *(const bf16x8*)(QH + off);
        ql[nt] = *(const bf16x8*)(QL + off);
    }

    f32x4 rs[4];
#pragma unroll
    for (int nt = 0; nt < 4; ++nt) rs[nt] = (f32x4){0.f, 0.f, 0.f, 0.f};

#pragma unroll 1
    for (int rep = 0; rep < REPEAT; ++rep) {
        // opaque barrier: compiler can't prove m0r is rep-invariant -> no LICM
        // hoisting of the W loads out of the rep loop (would defeat the probe)
        int m0r = blockIdx.y * 64;
        asm volatile("" : "+v"(m0r));
#pragma unroll 2
        for (int it = 0; it < 4; ++it) {
            const int mrow = m0r + it * 16 + r15;
            const size_t woff = (size_t)mrow * 64 + g * 8;
            bf16x8 wh0 = *(const bf16x8*)(WH + woff);
            bf16x8 wh1 = *(const bf16x8*)(WH + woff + 32);
            bf16x8 wl0 = *(const bf16x8*)(WL + woff);
            bf16x8 wl1 = *(const bf16x8*)(WL + woff + 32);
            const float a2 = A2[mrow];
#pragma unroll
            for (int nt = 0; nt < 4; ++nt) {
                f32x4 acc = (f32x4){0.f, 0.f, 0.f, 0.f};
                acc = __builtin_amdgcn_mfma_f32_16x16x32_bf16(xh[nt], wh0, acc, 0, 0, 0);
                acc = __builtin_amdgcn_mfma_f32_16x16x32_bf16(qh[nt], wh1, acc, 0, 0, 0);
                acc = __builtin_amdgcn_mfma_f32_16x16x32_bf16(xl[nt], wh0, acc, 0, 0, 0);
                acc = __builtin_amdgcn_mfma_f32_16x16x32_bf16(ql[nt], wh1, acc, 0, 0, 0);
                acc = __builtin_amdgcn_mfma_f32_16x16x32_bf16(xh[nt], wl0, acc, 0, 0, 0);
                acc = __builtin_amdgcn_mfma_f32_16x16x32_bf16(qh[nt], wl1, acc, 0, 0, 0);
#pragma unroll
                for (int r = 0; r < 4; ++r) rs[nt][r] += fast_exp2(acc[r] + a2);
            }
        }
    }

    // reduce over the 16 column-lanes (same lane>>4 group holds same rows)
#pragma unroll
    for (int o = 1; o < 16; o <<= 1)
#pragma unroll
        for (int nt = 0; nt < 4; ++nt)
#pragma unroll
            for (int r = 0; r < 4; ++r) rs[nt][r] += __shfl_xor(rs[nt][r], o);

    const float scale = 1.0f / REPEAT;
    if (r15 == 0) {
#pragma unroll
        for (int nt = 0; nt < 4; ++nt) {
            f32x4 o4;
#pragma unroll
            for (int r = 0; r < 4; ++r) o4[r] = rs[nt][r] * scale;
            *(f32x4*)(partial + (size_t)blockIdx.y * NS + n_base + nt * 16 + g * 4) = o4;
        }
    }
}

// Sum partials -> dist, block min/max -> atomics; last block finalizes out.
__global__ __launch_bounds__(256) void reduce_final(unsigned char* __restrict__ ws,
                                                    float* __restrict__ out) {
    const float* partial = (const float*)(ws + PART_OFF);
    float* dist = (float*)(ws + DIST_OFF);
    unsigned* mm = (unsigned*)(ws + MM_OFF);
    unsigned* cnt = (unsigned*)(ws + CNT_OFF);

    const int tid = threadIdx.x;
    const int n = blockIdx.x * 256 + tid;
    float v = 0.f;
#pragma unroll
    for (int j = 0; j < MSPLIT; ++j) v += partial[(size_t)j * NS + n];
    dist[n] = v;

    float mn = v, mx = v;
#pragma unroll
    for (int o = 1; o < 64; o <<= 1) {
        mn = fminf(mn, __shfl_xor(mn, o));
        mx = fmaxf(mx, __shfl_xor(mx, o));
    }
    __shared__ float smn[4], smx[4];
    __shared__ int lastFlag;
    const int wv = tid >> 6, ln = tid & 63;
    if (ln == 0) { smn[wv] = mn; smx[wv] = mx; }
    __syncthreads();
    if (tid == 0) {
#pragma unroll
        for (int j = 1; j < 4; ++j) {
            mn = fminf(mn, smn[j]);
            mx = fmaxf(mx, smx[j]);
        }
        atomicMin(mm + 0, __float_as_uint(mn));
        atomicMax(mm + 1, __float_as_uint(mx));
        __threadfence();
        unsigned old = atomicAdd(cnt, 1u);
        lastFlag = (old == (unsigned)(gridDim.x - 1));
    }
    __syncthreads();
    if (lastFlag) {
        __threadfence();
        volatile unsigned* vmm = mm;
        const float fmn = __uint_as_float(vmm[0]);
        const float fmx = __uint_as_float(vmm[1]);
        volatile float* vd = dist;
        for (int i = tid; i < NS; i += 256) out[i] = fmx + fmn - vd[i];
    }
}

extern "C" void kernel_launch(void* const* d_in, const int* in_sizes, int n_in,
                              void* d_out, int out_size, void* d_ws, size_t ws_size,
                              hipStream_t stream) {
    const float* samples = (const float*)d_in[0];
    const float* means   = (const float*)d_in[1];
    const float* stds    = (const float*)d_in[2];
    unsigned char* ws = (unsigned char*)d_ws;
    float* out = (float*)d_out;

    prep_kernel<<<dim3(64 + NS * DD / 4 / 256), 256, 0, stream>>>(samples, means, stds, ws);
    kde_mfma<<<dim3(NS / 256, MSPLIT), 256, 0, stream>>>(ws, (float*)(ws + PART_OFF));
    reduce_final<<<dim3(NS / 256), 256, 0, stream>>>(ws, out);
}

// Round 9
// 34.210 us; speedup vs baseline: 1.6756x; 1.6756x over previous
//
#include <hip/hip_runtime.h>

#define NS 8192
#define MS 2048
#define DD 32
#define MSPLIT 16
#define MCH (MS / MSPLIT)     // 128 m per block
#define NITS (MCH / 16)       // 8 m-tiles

typedef __attribute__((ext_vector_type(8))) short bf16x8;
typedef __attribute__((ext_vector_type(4))) float f32x4;
typedef unsigned short u16;

// ws byte offsets
#define PART_OFF 0                          // [MSPLIT][NS] f32 (512 KB)
#define DIST_OFF (MSPLIT * NS * 4)          // [NS] f32
#define MM_OFF   (DIST_OFF + NS * 4)        // 2 u32 (min,max bits)
#define CNT_OFF  (MM_OFF + 8)               // 1 u32

__device__ inline float fast_exp2(float x) {
#if __has_builtin(__builtin_amdgcn_exp2f)
    return __builtin_amdgcn_exp2f(x);
#else
    return exp2f(x);
#endif
}
__device__ inline u16 f2bf(float x) {  // round-to-nearest-even bf16
    unsigned u = __float_as_uint(x);
    return (u16)((u + 0x7fffu + ((u >> 16) & 1u)) >> 16);
}
__device__ inline float bf2f(u16 h) { return __uint_as_float(((unsigned)h) << 16); }

// Fused: per-block W->LDS conversion (fragment-order, conflict-free reads),
// in-register X split from raw samples, MFMA m-loop, partial write.
// NO device fences here: the kernel boundary is the release (R6: 512
// per-block __threadfence = L2 writebacks = 91us disaster).
__global__ __launch_bounds__(256, 2) void kde_fused(const float* __restrict__ samples,
                                                    const float* __restrict__ means,
                                                    const float* __restrict__ stds,
                                                    float* __restrict__ partial) {
    // fragment-order W: [it][g][r15][8] u16 — wave read = 1KB contiguous
    __shared__ u16 WBH[NITS * 4 * 16 * 8];
    __shared__ u16 WBL[NITS * 4 * 16 * 8];
    __shared__ u16 WCH[NITS * 4 * 16 * 8];
    __shared__ u16 WCL[NITS * 4 * 16 * 8];
    __shared__ float A2s[MCH];

    const int t = threadIdx.x;
    const int m0 = blockIdx.y * MCH;
    const float L2E = 1.4426950408889634f;

    // ---- phase 1: W chunk -> LDS (one thread per (m_local, 16-d half)) ----
    {
        const int ml = t >> 1, dh = (t & 1) * 16;
        const float* mp = means + (size_t)(m0 + ml) * DD + dh;
        const float* vp = stds  + (size_t)(m0 + ml) * DD + dh;
        float mu[16], sd[16];
#pragma unroll
        for (int j = 0; j < 4; ++j) {
            float4 a4 = *(const float4*)(mp + j * 4);
            float4 b4 = *(const float4*)(vp + j * 4);
            mu[j*4+0]=a4.x; mu[j*4+1]=a4.y; mu[j*4+2]=a4.z; mu[j*4+3]=a4.w;
            sd[j*4+0]=b4.x; sd[j*4+1]=b4.y; sd[j*4+2]=b4.z; sd[j*4+3]=b4.w;
        }
        float Bv[16], Cv[16], a = 0.f;
#pragma unroll
        for (int j = 0; j < 16; ++j) {
            float inv = 1.0f / sd[j];
            Bv[j] = L2E * mu[j] * inv;
            Cv[j] = -0.5f * L2E * inv;
            a += mu[j] * mu[j] * inv;
        }
        a += __shfl_xor(a, 1);  // combine the two d-halves of row ml
        if (!(t & 1)) A2s[ml] = -0.5f * L2E * a - 11.0f;  // -log2(M): mean folded in

        const int it = ml >> 4, r15 = ml & 15;
#pragma unroll
        for (int r2 = 0; r2 < 2; ++r2) {
            bf16x8 bh, bl, ch, cl;
#pragma unroll
            for (int e = 0; e < 8; ++e) {
                float B = Bv[r2 * 8 + e];
                u16 h = f2bf(B);
                bh[e] = (short)h; bl[e] = (short)f2bf(B - bf2f(h));
                float C = Cv[r2 * 8 + e];
                h = f2bf(C);
                ch[e] = (short)h; cl[e] = (short)f2bf(C - bf2f(h));
            }
            const int g = (dh >> 3) + r2;
            const int base = ((it * 4 + g) * 16 + r15) * 8;
            *(bf16x8*)&WBH[base] = bh;
            *(bf16x8*)&WBL[base] = bl;
            *(bf16x8*)&WCH[base] = ch;
            *(bf16x8*)&WCL[base] = cl;
        }
    }

    // ---- phase 2: X fragments straight from samples ----
    const int lane = t & 63, wid = t >> 6;
    const int r15 = lane & 15, g = lane >> 4;
    const int n0 = blockIdx.x * 256 + wid * 64;

    bf16x8 xh[4], xl[4], qh[4], ql[4];
#pragma unroll
    for (int nt = 0; nt < 4; ++nt) {
        const float* sp = samples + (size_t)(n0 + nt * 16 + r15) * DD + g * 8;
        float4 a4 = *(const float4*)sp, b4 = *(const float4*)(sp + 4);
        float xv[8] = {a4.x, a4.y, a4.z, a4.w, b4.x, b4.y, b4.z, b4.w};
#pragma unroll
        for (int j = 0; j < 8; ++j) {
            u16 h = f2bf(xv[j]);
            xh[nt][j] = (short)h;
            xl[nt][j] = (short)f2bf(xv[j] - bf2f(h));
            float q = xv[j] * xv[j];
            h = f2bf(q);
            qh[nt][j] = (short)h;
            ql[nt][j] = (short)f2bf(q - bf2f(h));
        }
    }

    __syncthreads();

    // ---- phase 3: m-loop over LDS-resident W ----
    f32x4 rs[4];
#pragma unroll
    for (int nt = 0; nt < 4; ++nt) rs[nt] = (f32x4){0.f, 0.f, 0.f, 0.f};

#pragma unroll 2
    for (int it = 0; it < NITS; ++it) {
        const int base = ((it * 4 + g) * 16 + r15) * 8;
        bf16x8 bh = *(const bf16x8*)&WBH[base];
        bf16x8 ch = *(const bf16x8*)&WCH[base];
        bf16x8 bl = *(const bf16x8*)&WBL[base];
        bf16x8 cl = *(const bf16x8*)&WCL[base];
        const float a2 = A2s[it * 16 + r15];
#pragma unroll
        for (int nt = 0; nt < 4; ++nt) {
            f32x4 acc = (f32x4){0.f, 0.f, 0.f, 0.f};
            acc = __builtin_amdgcn_mfma_f32_16x16x32_bf16(xh[nt], bh, acc, 0, 0, 0);
            acc = __builtin_amdgcn_mfma_f32_16x16x32_bf16(qh[nt], ch, acc, 0, 0, 0);
            acc = __builtin_amdgcn_mfma_f32_16x16x32_bf16(xl[nt], bh, acc, 0, 0, 0);
            acc = __builtin_amdgcn_mfma_f32_16x16x32_bf16(ql[nt], ch, acc, 0, 0, 0);
            acc = __builtin_amdgcn_mfma_f32_16x16x32_bf16(xh[nt], bl, acc, 0, 0, 0);
            acc = __builtin_amdgcn_mfma_f32_16x16x32_bf16(qh[nt], cl, acc, 0, 0, 0);
#pragma unroll
            for (int r = 0; r < 4; ++r) rs[nt][r] += fast_exp2(acc[r] + a2);
        }
    }

    // sum the 16 m-columns (lanes sharing g)
#pragma unroll
    for (int o = 1; o < 16; o <<= 1)
#pragma unroll
        for (int nt = 0; nt < 4; ++nt)
#pragma unroll
            for (int r = 0; r < 4; ++r) rs[nt][r] += __shfl_xor(rs[nt][r], o);

    if (r15 == 0) {
#pragma unroll
        for (int nt = 0; nt < 4; ++nt)
            *(f32x4*)(partial + (size_t)blockIdx.y * NS + n0 + nt * 16 + g * 4) = rs[nt];
    }
}

// Sum partials -> dist, block min/max -> atomics; last block finalizes out.
__global__ __launch_bounds__(256) void reduce_final(unsigned char* __restrict__ ws,
                                                    float* __restrict__ out) {
    const float* partial = (const float*)(ws + PART_OFF);
    float* dist = (float*)(ws + DIST_OFF);
    unsigned* mm = (unsigned*)(ws + MM_OFF);
    unsigned* cnt = (unsigned*)(ws + CNT_OFF);

    const int tid = threadIdx.x;
    const int n = blockIdx.x * 256 + tid;
    float v = 0.f;
#pragma unroll
    for (int j = 0; j < MSPLIT; ++j) v += partial[(size_t)j * NS + n];
    dist[n] = v;

    float mn = v, mx = v;
#pragma unroll
    for (int o = 1; o < 64; o <<= 1) {
        mn = fminf(mn, __shfl_xor(mn, o));
        mx = fmaxf(mx, __shfl_xor(mx, o));
    }
    __shared__ float smn[4], smx[4];
    __shared__ int lastFlag;
    const int wv = tid >> 6, ln = tid & 63;
    if (ln == 0) { smn[wv] = mn; smx[wv] = mx; }
    __syncthreads();
    if (tid == 0) {
#pragma unroll
        for (int j = 1; j < 4; ++j) {
            mn = fminf(mn, smn[j]);
            mx = fmaxf(mx, smx[j]);
        }
        atomicMin(mm + 0, __float_as_uint(mn));
        atomicMax(mm + 1, __float_as_uint(mx));
        __threadfence();
        unsigned old = atomicAdd(cnt, 1u);
        lastFlag = (old == (unsigned)(gridDim.x - 1));
    }
    __syncthreads();
    if (lastFlag) {
        __threadfence();
        volatile unsigned* vmm = mm;
        const float fmn = __uint_as_float(vmm[0]);
        const float fmx = __uint_as_float(vmm[1]);
        volatile float* vd = dist;
        for (int i = tid; i < NS; i += 256) out[i] = fmx + fmn - vd[i];
    }
}

extern "C" void kernel_launch(void* const* d_in, const int* in_sizes, int n_in,
                              void* d_out, int out_size, void* d_ws, size_t ws_size,
                              hipStream_t stream) {
    const float* samples = (const float*)d_in[0];
    const float* means   = (const float*)d_in[1];
    const float* stds    = (const float*)d_in[2];
    unsigned char* ws = (unsigned char*)d_ws;
    float* out = (float*)d_out;

    // min slot = 0xFFFFFFFF (unsigned atomicMin init); max slot + counter = 0
    hipMemsetAsync(ws + MM_OFF, 0xFF, 4, stream);
    hipMemsetAsync(ws + MM_OFF + 4, 0, 8, stream);
    kde_fused<<<dim3(NS / 256, MSPLIT), 256, 0, stream>>>(samples, means, stds,
                                                          (float*)(ws + PART_OFF));
    reduce_final<<<dim3(NS / 256), 256, 0, stream>>>(ws, out);
}

// Round 10
// 26.664 us; speedup vs baseline: 2.1497x; 1.2830x over previous
//
#include <hip/hip_runtime.h>

#define NS 8192
#define MS 2048
#define DD 32
#define MSPLIT 32
#define MCH (MS / MSPLIT)     // 64 m per block
#define NITS (MCH / 16)       // 4 m-tiles

typedef __attribute__((ext_vector_type(8))) short bf16x8;
typedef __attribute__((ext_vector_type(4))) float f32x4;
typedef unsigned short u16;
typedef unsigned int u32;

// ws byte offsets
#define PART_OFF 0                          // [MSPLIT][NS] f32 (1 MB)
#define DIST_OFF (MSPLIT * NS * 4)          // [NS] f32
#define MM_OFF   (DIST_OFF + NS * 4)        // 2 u32 (min,max bits)
#define CNT_OFF  (MM_OFF + 8)               // 1 u32

__device__ inline float fast_exp2(float x) {
#if __has_builtin(__builtin_amdgcn_exp2f)
    return __builtin_amdgcn_exp2f(x);
#else
    return exp2f(x);
#endif
}

// 2x f32 -> packed bf16 pair, RNE, one instruction (no builtin on gfx950).
__device__ inline u32 cvt_pk_bf16(float a, float b) {
    u32 r;
    asm("v_cvt_pk_bf16_f32 %0, %1, %2" : "=v"(r) : "v"(a), "v"(b));
    return r;
}

// Split 8 floats into hi/lo bf16x8. Pack-order of cvt_pk is irrelevant to
// correctness: X and W use the same helper, so the MFMA dot pairs identical
// k-elements either way.
__device__ inline void split8(const float* v, bf16x8& hi, bf16x8& lo) {
    union { u32 u[4]; bf16x8 b; } H, L;
#pragma unroll
    for (int j = 0; j < 4; ++j) {
        u32 h = cvt_pk_bf16(v[2 * j], v[2 * j + 1]);
        float ha = __uint_as_float(h << 16);            // bf2f(low half)
        float hb = __uint_as_float(h & 0xFFFF0000u);    // bf2f(high half)
        L.u[j] = cvt_pk_bf16(v[2 * j] - ha, v[2 * j + 1] - hb);
        H.u[j] = h;
    }
    hi = H.b;
    lo = L.b;
}

// Fused: per-block W->LDS conversion (fragment-order, conflict-free),
// in-register X split from raw samples, MFMA m-loop, partial write.
// Block (0,0) also (re)inits the min/max/counter slots each call — replaces
// the two hipMemsetAsync graph nodes (each cost a full node's overhead).
__global__ __launch_bounds__(256, 4) void kde_fused(const float* __restrict__ samples,
                                                    const float* __restrict__ means,
                                                    const float* __restrict__ stds,
                                                    unsigned char* __restrict__ wsb) {
    __shared__ u16 WBH[NITS * 4 * 16 * 8];   // [it][g][r15][8]
    __shared__ u16 WBL[NITS * 4 * 16 * 8];
    __shared__ u16 WCH[NITS * 4 * 16 * 8];
    __shared__ u16 WCL[NITS * 4 * 16 * 8];
    __shared__ float A2s[MCH];

    const int t = threadIdx.x;
    const int m0 = blockIdx.y * MCH;
    const float L2E = 1.4426950408889634f;

    if (blockIdx.x == 0 && blockIdx.y == 0 && t == 0) {
        unsigned* mm = (unsigned*)(wsb + MM_OFF);
        mm[0] = 0x7f7fffffu;  // FLT_MAX bits (uint cmp == float cmp for positives)
        mm[1] = 0u;
        *(unsigned*)(wsb + CNT_OFF) = 0u;
    }

    // ---- phase 1: W chunk -> LDS, one thread per (m_local, 8-d quarter) ----
    {
        const int ml = t >> 2, qd = t & 3;
        const float* mp = means + (size_t)(m0 + ml) * DD + qd * 8;
        const float* vp = stds  + (size_t)(m0 + ml) * DD + qd * 8;
        float4 a4 = *(const float4*)mp, b4 = *(const float4*)(mp + 4);
        float4 c4 = *(const float4*)vp, d4 = *(const float4*)(vp + 4);
        float mu[8] = {a4.x, a4.y, a4.z, a4.w, b4.x, b4.y, b4.z, b4.w};
        float sd[8] = {c4.x, c4.y, c4.z, c4.w, d4.x, d4.y, d4.z, d4.w};
        float Bv[8], Cv[8], a = 0.f;
#pragma unroll
        for (int j = 0; j < 8; ++j) {
            float inv = 1.0f / sd[j];
            Bv[j] = L2E * mu[j] * inv;
            Cv[j] = -0.5f * L2E * inv;
            a += mu[j] * mu[j] * inv;
        }
        a += __shfl_xor(a, 1);
        a += __shfl_xor(a, 2);
        if (qd == 0) A2s[ml] = -0.5f * L2E * a - 11.0f;  // -log2(M) folds the mean

        bf16x8 bh, bl, ch, cl;
        split8(Bv, bh, bl);
        split8(Cv, ch, cl);
        const int it = ml >> 4, r15 = ml & 15;
        const int base = ((it * 4 + qd) * 16 + r15) * 8;
        *(bf16x8*)&WBH[base] = bh;
        *(bf16x8*)&WBL[base] = bl;
        *(bf16x8*)&WCH[base] = ch;
        *(bf16x8*)&WCL[base] = cl;
    }

    // ---- phase 2: X fragments straight from samples ----
    const int lane = t & 63, wid = t >> 6;
    const int r15 = lane & 15, g = lane >> 4;
    const int n0 = blockIdx.x * 256 + wid * 64;

    bf16x8 xh[4], xl[4], qh[4], ql[4];
#pragma unroll
    for (int nt = 0; nt < 4; ++nt) {
        const float* sp = samples + (size_t)(n0 + nt * 16 + r15) * DD + g * 8;
        float4 a4 = *(const float4*)sp, b4 = *(const float4*)(sp + 4);
        float xv[8] = {a4.x, a4.y, a4.z, a4.w, b4.x, b4.y, b4.z, b4.w};
        float qv[8];
#pragma unroll
        for (int j = 0; j < 8; ++j) qv[j] = xv[j] * xv[j];
        split8(xv, xh[nt], xl[nt]);
        split8(qv, qh[nt], ql[nt]);
    }

    __syncthreads();

    // ---- phase 3: m-loop over LDS-resident W ----
    f32x4 rs[4];
#pragma unroll
    for (int nt = 0; nt < 4; ++nt) rs[nt] = (f32x4){0.f, 0.f, 0.f, 0.f};

#pragma unroll 2
    for (int it = 0; it < NITS; ++it) {
        const int base = ((it * 4 + g) * 16 + r15) * 8;
        bf16x8 bh = *(const bf16x8*)&WBH[base];
        bf16x8 ch = *(const bf16x8*)&WCH[base];
        bf16x8 bl = *(const bf16x8*)&WBL[base];
        bf16x8 cl = *(const bf16x8*)&WCL[base];
        const float a2 = A2s[it * 16 + r15];
#pragma unroll
        for (int nt = 0; nt < 4; ++nt) {
            f32x4 acc = (f32x4){0.f, 0.f, 0.f, 0.f};
            acc = __builtin_amdgcn_mfma_f32_16x16x32_bf16(xh[nt], bh, acc, 0, 0, 0);
            acc = __builtin_amdgcn_mfma_f32_16x16x32_bf16(qh[nt], ch, acc, 0, 0, 0);
            acc = __builtin_amdgcn_mfma_f32_16x16x32_bf16(xl[nt], bh, acc, 0, 0, 0);
            acc = __builtin_amdgcn_mfma_f32_16x16x32_bf16(ql[nt], ch, acc, 0, 0, 0);
            acc = __builtin_amdgcn_mfma_f32_16x16x32_bf16(xh[nt], bl, acc, 0, 0, 0);
            acc = __builtin_amdgcn_mfma_f32_16x16x32_bf16(qh[nt], cl, acc, 0, 0, 0);
#pragma unroll
            for (int r = 0; r < 4; ++r) rs[nt][r] += fast_exp2(acc[r] + a2);
        }
    }

    // sum the 16 m-columns (lanes sharing g)
#pragma unroll
    for (int o = 1; o < 16; o <<= 1)
#pragma unroll
        for (int nt = 0; nt < 4; ++nt)
#pragma unroll
            for (int r = 0; r < 4; ++r) rs[nt][r] += __shfl_xor(rs[nt][r], o);

    float* partial = (float*)(wsb + PART_OFF);
    if (r15 == 0) {
#pragma unroll
        for (int nt = 0; nt < 4; ++nt)
            *(f32x4*)(partial + (size_t)blockIdx.y * NS + n0 + nt * 16 + g * 4) = rs[nt];
    }
}

// Sum partials -> dist, block min/max -> atomics; last block finalizes out.
__global__ __launch_bounds__(256) void reduce_final(unsigned char* __restrict__ ws,
                                                    float* __restrict__ out) {
    const float* partial = (const float*)(ws + PART_OFF);
    float* dist = (float*)(ws + DIST_OFF);
    unsigned* mm = (unsigned*)(ws + MM_OFF);
    unsigned* cnt = (unsigned*)(ws + CNT_OFF);

    const int tid = threadIdx.x;
    const int n = blockIdx.x * 256 + tid;
    float v = 0.f;
#pragma unroll
    for (int j = 0; j < MSPLIT; ++j) v += partial[(size_t)j * NS + n];
    dist[n] = v;

    float mn = v, mx = v;
#pragma unroll
    for (int o = 1; o < 64; o <<= 1) {
        mn = fminf(mn, __shfl_xor(mn, o));
        mx = fmaxf(mx, __shfl_xor(mx, o));
    }
    __shared__ float smn[4], smx[4];
    __shared__ int lastFlag;
    const int wv = tid >> 6, ln = tid & 63;
    if (ln == 0) { smn[wv] = mn; smx[wv] = mx; }
    __syncthreads();
    if (tid == 0) {
#pragma unroll
        for (int j = 1; j < 4; ++j) {
            mn = fminf(mn, smn[j]);
            mx = fmaxf(mx, smx[j]);
        }
        atomicMin(mm + 0, __float_as_uint(mn));
        atomicMax(mm + 1, __float_as_uint(mx));
        __threadfence();
        unsigned old = atomicAdd(cnt, 1u);
        lastFlag = (old == (unsigned)(gridDim.x - 1));
    }
    __syncthreads();
    if (lastFlag) {
        __threadfence();
        volatile unsigned* vmm = mm;
        const float fmn = __uint_as_float(vmm[0]);
        const float fmx = __uint_as_float(vmm[1]);
        volatile float* vd = dist;
        for (int i = tid; i < NS; i += 256) out[i] = fmx + fmn - vd[i];
    }
}

extern "C" void kernel_launch(void* const* d_in, const int* in_sizes, int n_in,
                              void* d_out, int out_size, void* d_ws, size_t ws_size,
                              hipStream_t stream) {
    const float* samples = (const float*)d_in[0];
    const float* means   = (const float*)d_in[1];
    const float* stds    = (const float*)d_in[2];
    unsigned char* ws = (unsigned char*)d_ws;
    float* out = (float*)d_out;

    kde_fused<<<dim3(NS / 256, MSPLIT), 256, 0, stream>>>(samples, means, stds, ws);
    reduce_final<<<dim3(NS / 256), 256, 0, stream>>>(ws, out);
}